// Round 10
// baseline (243.920 us; speedup 1.0000x reference)
//
#include <hip/hip_runtime.h>

#define N_NODES 50000
#define N_EDGES 640000
#define N_SUP   3
#define D       128
#define NTOT    150000                   // 3 * 50000 global rows
#define E_TOT   1920000
#define NC      293                      // 512-row coarse buckets (grow>>9)
#define CAPC    7680                     // raw cap: mean 6553 + ~14 sigma
#define CAPB    9216                     // padded cap: CAPC + 512*3
#define CTILE   2048
#define CTPS    313                      // ceil(640000/2048) tiles per support
#define SBLKS   (N_SUP * CTPS)           // 939 scatter blocks
#define XCBLKS  6250                     // (50000*128/4)/256 x-convert blocks
#define WBLKS   192                      // 49152/256 W-pack blocks
#define NWAVES  (N_NODES / 16)           // 3125 gemm waves

typedef __attribute__((ext_vector_type(2))) float f32x2;
typedef __attribute__((ext_vector_type(4))) float f32x4;
typedef __attribute__((ext_vector_type(8))) short s16x8;

__device__ __forceinline__ unsigned short f2bf(float f) {   // RNE
    unsigned int u = __float_as_uint(f);
    u += 0x7FFFu + ((u >> 16) & 1u);
    return (unsigned short)(u >> 16);
}

// ---------------------------------------------------------------------------
// Fused prep + coarse scatter. Blocks [0,SBLKS): scatter edges into 293
// coarse buckets (2048-edge register-staged tiles, LDS bucket histogram, one
// global atomic reserve per bucket per tile; coarse_wptr is ZERO-BASED so a
// memset replaces pointer init). Scatter blocks come FIRST (critical path);
// the x->bf16 and W->frag conversions fill trailing dispatch capacity.
// meta = (local_row<<16) | col.
// ---------------------------------------------------------------------------
__global__ __launch_bounds__(256) void prep_scatter(
    const int* __restrict__ rows, const int* __restrict__ cols,
    const float* __restrict__ vals, int* __restrict__ coarse_wptr,
    uint2* __restrict__ sortedA,
    const float4* __restrict__ x, ushort4* __restrict__ xb,
    const float* __restrict__ W, unsigned short* __restrict__ Wf)
{
    __shared__ int h[NC], base[NC];
    int tid = threadIdx.x;

    if (blockIdx.x >= SBLKS) {                   // -------- convert path ----
        int gid = (blockIdx.x - SBLKS) * 256 + tid;
        if (gid < N_NODES * D / 4) {             // x -> bf16
            float4 v = x[gid];
            ushort4 o;
            o.x = f2bf(v.x); o.y = f2bf(v.y); o.z = f2bf(v.z); o.w = f2bf(v.w);
            xb[gid] = o;
        } else {                                 // W -> MFMA B-fragment order
            int g2 = gid - N_NODES * D / 4;
            if (g2 < N_SUP * D * D) {
                int j    = g2 & 7;
                int lane = (g2 >> 3) & 63;
                int rest = g2 >> 9;
                int nt = rest & 7, kb = (rest >> 3) & 3, s = rest >> 5;
                int k = kb * 32 + ((lane >> 4) * 8) + j;
                int n = nt * 16 + (lane & 15);
                Wf[g2] = f2bf(W[((size_t)s * D + k) * D + n]);
            }
        }
        return;
    }

    // ------------------------------- scatter path -------------------------
    for (int i = tid; i < NC; i += 256) h[i] = 0;
    __syncthreads();

    int s  = blockIdx.x / CTPS;
    int tb = (blockIdx.x % CTPS) * CTILE;
    int n  = N_EDGES - tb; if (n > CTILE) n = CTILE;
    const int*   rp = rows + (size_t)s * N_EDGES + tb;
    const int*   cp = cols + (size_t)s * N_EDGES + tb;
    const float* vp = vals + (size_t)s * N_EDGES + tb;

    int bk[8], grow[8];
    #pragma unroll
    for (int i = 0; i < 8; ++i) {
        int idx = tid + i * 256;
        bk[i] = -1;
        if (idx < n) {
            grow[i] = s * N_NODES + rp[idx];
            bk[i] = grow[i] >> 9;
            atomicAdd(&h[bk[i]], 1);
        }
    }
    __syncthreads();
    for (int i = tid; i < NC; i += 256) {
        base[i] = atomicAdd(&coarse_wptr[i], h[i]);   // zero-based count
        h[i] = 0;                                     // reuse as running rank
    }
    __syncthreads();
    #pragma unroll
    for (int i = 0; i < 8; ++i) {
        int idx = tid + i * 256;
        if (idx < n) {
            int rank = atomicAdd(&h[bk[i]], 1);
            int slot = base[bk[i]] + rank;
            if (slot < CAPC) {                   // never at +14 sigma
                unsigned int meta = ((unsigned int)(grow[i] & 511) << 16)
                                  | (unsigned int)cp[idx];
                sortedA[(size_t)bk[i] * CAPC + slot] =
                    make_uint2(meta, __float_as_uint(vp[idx]));
            }
        }
    }
}

// ---------------------------------------------------------------------------
// Bucket sort, 4-way row-split for occupancy (1172 blocks vs 293): block
// (c,q) streams the WHOLE bucket (L2-hot), builds the full 512-row LDS
// histogram + scan (rows padded to x4 edges), then scatters only rows
// [q*128,(q+1)*128) into the fixed-capacity CAPB region and zero-fills its
// pad slots. q=0 also writes row_ptr2 (513 entries/bucket, last = end).
// ---------------------------------------------------------------------------
__global__ __launch_bounds__(512) void bucket_sort(
    const int* __restrict__ coarse_wptr, const uint2* __restrict__ sortedA,
    int* __restrict__ row_ptr2, unsigned int* __restrict__ sortedB)
{
    int c  = blockIdx.x >> 2;
    int q  = blockIdx.x & 3;
    int cnt = coarse_wptr[c];
    if (cnt > CAPC) cnt = CAPC;
    int rowlo = q * 128;

    __shared__ int hist[512];
    __shared__ int rank[128];
    __shared__ int fin[128];
    int tid = threadIdx.x;
    hist[tid] = 0;
    __syncthreads();

    const uint2* src = sortedA + (size_t)c * CAPC;
    for (int i = tid; i < cnt; i += 512)
        atomicAdd(&hist[src[i].x >> 16], 1);
    __syncthreads();

    int padded = (hist[tid] + 3) & ~3;           // rows padded to x4 edges
    hist[tid] = padded;
    __syncthreads();
    for (int off = 1; off < 512; off <<= 1) {    // inclusive scan of padded
        int t = (tid >= off) ? hist[tid - off] : 0;
        __syncthreads();
        hist[tid] += t;
        __syncthreads();
    }
    int start = c * CAPB + hist[tid] - padded;
    if ((unsigned)(tid - rowlo) < 128u) {
        rank[tid - rowlo] = start;
        fin [tid - rowlo] = start + padded;
    }
    if (q == 0) {
        row_ptr2[c * 513 + tid] = start;
        if (tid == 511) row_ptr2[c * 513 + 512] = c * CAPB + hist[511];
    }
    __syncthreads();

    auto proc = [&](uint2 e) {
        int lr = (int)(e.x >> 16) - rowlo;
        if ((unsigned)lr < 128u) {
            int r = atomicAdd(&rank[lr], 1);
            sortedB[r] = ((unsigned int)f2bf(__uint_as_float(e.y)) << 16)
                       | (e.x & 0xFFFFu);
        }
    };
    int i = tid;
    for (; i + 1536 < cnt; i += 2048) {          // 4-deep ILP on the loads
        uint2 e0 = src[i], e1 = src[i + 512];
        uint2 e2 = src[i + 1024], e3 = src[i + 1536];
        proc(e0); proc(e1); proc(e2); proc(e3);
    }
    for (; i < cnt; i += 512) proc(src[i]);
    __syncthreads();

    if (tid < 128)                               // zero-fill pads (<=3/row)
        for (int p = rank[tid]; p < fin[tid]; ++p) sortedB[p] = 0;
}

// ---------------------------------------------------------------------------
// Gather-SpMM (proven R9): wave = 2 halves of 32 lanes, 4 edges in flight,
// rows padded to x4 -> no clamps; float2 accs -> v_pk_fma_f32.
// ---------------------------------------------------------------------------
__global__ __launch_bounds__(256) void spmm_gather(
    const unsigned short* __restrict__ xb, const int* __restrict__ row_ptr2,
    const unsigned int* __restrict__ sortedB, unsigned short* __restrict__ Yb)
{
    int wid  = (blockIdx.x * 256 + threadIdx.x) >> 6;
    int lane = threadIdx.x & 63;
    if (wid >= NTOT) return;
    int rpi   = (wid >> 9) * 513 + (wid & 511);
    int start = row_ptr2[rpi];
    int end   = row_ptr2[rpi + 1];
    const int hh = lane >> 5;                    // half index
    const int u  = lane & 31;                    // cols 4u..4u+3
    f32x2 accA = {0.f, 0.f}, accB = {0.f, 0.f};

    for (int j = start; j < end; j += 64) {
        int m = end - j; if (m > 64) m = 64;     // multiple of 4
        unsigned int ev = (lane < m) ? sortedB[j + lane] : 0u;
        for (int t = 0; t < m; t += 4) {
            unsigned int e0 = (unsigned int)__shfl((int)ev, t + hh);
            unsigned int e1 = (unsigned int)__shfl((int)ev, t + 2 + hh);
            float v0 = __uint_as_float(e0 & 0xFFFF0000u);
            float v1 = __uint_as_float(e1 & 0xFFFF0000u);
            uint2 X0 = *((const uint2*)(xb + (size_t)(e0 & 0xFFFFu) * D) + u);
            uint2 X1 = *((const uint2*)(xb + (size_t)(e1 & 0xFFFFu) * D) + u);
            f32x2 xa0 = {__uint_as_float(X0.x << 16),
                         __uint_as_float(X0.x & 0xFFFF0000u)};
            f32x2 xb0 = {__uint_as_float(X0.y << 16),
                         __uint_as_float(X0.y & 0xFFFF0000u)};
            f32x2 xa1 = {__uint_as_float(X1.x << 16),
                         __uint_as_float(X1.x & 0xFFFF0000u)};
            f32x2 xb1 = {__uint_as_float(X1.y << 16),
                         __uint_as_float(X1.y & 0xFFFF0000u)};
            accA += v0 * xa0;                    // v_pk_fma_f32
            accB += v0 * xb0;
            accA += v1 * xa1;
            accB += v1 * xb1;
        }
    }
    float a0 = accA.x, a1 = accA.y, a2 = accB.x, a3 = accB.y;
    a0 += __shfl_xor(a0, 32);
    a1 += __shfl_xor(a1, 32);
    a2 += __shfl_xor(a2, 32);
    a3 += __shfl_xor(a3, 32);
    if (hh == 0) {
        uint2 o;
        o.x = (unsigned int)f2bf(a0) | ((unsigned int)f2bf(a1) << 16);
        o.y = (unsigned int)f2bf(a2) | ((unsigned int)f2bf(a3) << 16);
        ((uint2*)(Yb + (size_t)wid * D))[u] = o;
    }
}

// ---------------------------------------------------------------------------
// MFMA GEMM: out = relu(bias + sum_s Y_s @ W_s)  (proven R3).
// ---------------------------------------------------------------------------
__global__ __launch_bounds__(256) void gemm_mfma(
    const unsigned short* __restrict__ Yb,
    const unsigned short* __restrict__ Wf,
    const float* __restrict__ bias,
    float* __restrict__ out)
{
    int wid  = blockIdx.x * 4 + (threadIdx.x >> 6);
    int lane = threadIdx.x & 63;
    if (wid >= NWAVES) return;
    const int m0   = wid * 16;
    const int quad = lane >> 4;
    const int l16  = lane & 15;

    f32x4 acc[8];
    #pragma unroll
    for (int nt = 0; nt < 8; ++nt) acc[nt] = (f32x4){0.f, 0.f, 0.f, 0.f};

    #pragma unroll
    for (int s = 0; s < N_SUP; ++s) {
        const unsigned short* ys = Yb + (size_t)s * N_NODES * D;
        #pragma unroll
        for (int kb = 0; kb < 4; ++kb) {
            s16x8 a = *(const s16x8*)(ys + (size_t)(m0 + l16) * D + kb * 32 + quad * 8);
            const unsigned short* wf = Wf + (size_t)((s * 4 + kb) * 8) * 64 * 8 + lane * 8;
            #pragma unroll
            for (int nt = 0; nt < 8; ++nt) {
                s16x8 bfrag = *(const s16x8*)(wf + (size_t)nt * 64 * 8);
                acc[nt] = __builtin_amdgcn_mfma_f32_16x16x32_bf16(a, bfrag, acc[nt], 0, 0, 0);
            }
        }
    }

    #pragma unroll
    for (int nt = 0; nt < 8; ++nt) {
        int col = nt * 16 + l16;
        float bv = bias[col];
        #pragma unroll
        for (int r = 0; r < 4; ++r) {
            int row = m0 + quad * 4 + r;
            out[(size_t)row * D + col] = fmaxf(acc[nt][r] + bv, 0.f);
        }
    }
}

extern "C" void kernel_launch(void* const* d_in, const int* in_sizes, int n_in,
                              void* d_out, int out_size, void* d_ws, size_t ws_size,
                              hipStream_t stream)
{
    const float* x         = (const float*)d_in[0];
    const int*   edge_rows = (const int*)  d_in[1];
    const int*   edge_cols = (const int*)  d_in[2];
    const float* edge_vals = (const float*)d_in[3];
    const float* weights   = (const float*)d_in[4];
    const float* bias      = (const float*)d_in[5];
    float* out = (float*)d_out;

    // workspace layout (256B aligned), ~81 MB total (ws >= 94 MB proven R2)
    char* ws = (char*)d_ws;
    size_t off = 0;
    auto alloc = [&](size_t bytes) -> char* {
        char* p = ws + off;
        off += (bytes + 255) & ~(size_t)255;
        return p;
    };
    int*            coarse_wptr = (int*)            alloc(NC * 4);
    int*            row_ptr2    = (int*)            alloc((size_t)NC * 513 * 4);
    unsigned short* xb          = (unsigned short*) alloc((size_t)N_NODES * D * 2);
    unsigned short* Wf          = (unsigned short*) alloc((size_t)N_SUP * D * D * 2);
    uint2*          sortedA     = (uint2*)          alloc((size_t)NC * CAPC * 8);
    unsigned int*   sortedB     = (unsigned int*)   alloc((size_t)NC * CAPB * 4);
    unsigned short* Yb          = (unsigned short*) alloc((size_t)NTOT * D * 2);

    hipMemsetAsync(coarse_wptr, 0, NC * 4, stream);
    prep_scatter<<<SBLKS + XCBLKS + WBLKS, 256, 0, stream>>>(
        edge_rows, edge_cols, edge_vals, coarse_wptr, sortedA,
        (const float4*)x, (ushort4*)xb, weights, Wf);
    bucket_sort <<<NC * 4, 512, 0, stream>>>(coarse_wptr, sortedA,
                                             row_ptr2, sortedB);
    spmm_gather <<<NTOT / 4, 256, 0, stream>>>(xb, row_ptr2, sortedB, Yb);
    gemm_mfma   <<<(NWAVES + 3) / 4, 256, 0, stream>>>(Yb, Wf, bias, out);
}

// Round 11
// 228.446 us; speedup vs baseline: 1.0677x; 1.0677x over previous
//
#include <hip/hip_runtime.h>

#define N_NODES 50000
#define N_EDGES 640000
#define N_SUP   3
#define D       128
#define NTOT    150000                   // 3 * 50000 global rows
#define E_TOT   1920000
#define NC      293                      // 512-row coarse buckets (grow>>9)
#define CAPC    7680                     // raw cap: mean 6553 + ~14 sigma
#define CAPB    9216                     // padded cap: CAPC + 512*3
#define CTILE   2048
#define CTPS    313                      // ceil(640000/2048) tiles per support
#define SBLKS   (N_SUP * CTPS)           // 939 scatter blocks
#define XCBLKS  6250                     // (50000*128/4)/256 x-convert blocks
#define WBLKS   192                      // 49152/256 W-pack blocks
#define LDSTR   132                      // LDS row stride in shorts (128+4 pad)

typedef __attribute__((ext_vector_type(2))) float f32x2;
typedef __attribute__((ext_vector_type(4))) float f32x4;
typedef __attribute__((ext_vector_type(8))) short s16x8;

__device__ __forceinline__ unsigned short f2bf(float f) {   // RNE
    unsigned int u = __float_as_uint(f);
    u += 0x7FFFu + ((u >> 16) & 1u);
    return (unsigned short)(u >> 16);
}

// ---------------------------------------------------------------------------
// Fused prep + coarse scatter (proven R10). Scatter blocks first (critical
// path); x->bf16 and W->frag conversions fill trailing capacity.
// meta = (local_row<<16) | col.
// ---------------------------------------------------------------------------
__global__ __launch_bounds__(256) void prep_scatter(
    const int* __restrict__ rows, const int* __restrict__ cols,
    const float* __restrict__ vals, int* __restrict__ coarse_wptr,
    uint2* __restrict__ sortedA,
    const float4* __restrict__ x, ushort4* __restrict__ xb,
    const float* __restrict__ W, unsigned short* __restrict__ Wf)
{
    __shared__ int h[NC], base[NC];
    int tid = threadIdx.x;

    if (blockIdx.x >= SBLKS) {                   // -------- convert path ----
        int gid = (blockIdx.x - SBLKS) * 256 + tid;
        if (gid < N_NODES * D / 4) {             // x -> bf16
            float4 v = x[gid];
            ushort4 o;
            o.x = f2bf(v.x); o.y = f2bf(v.y); o.z = f2bf(v.z); o.w = f2bf(v.w);
            xb[gid] = o;
        } else {                                 // W -> MFMA B-fragment order
            int g2 = gid - N_NODES * D / 4;
            if (g2 < N_SUP * D * D) {
                int j    = g2 & 7;
                int lane = (g2 >> 3) & 63;
                int rest = g2 >> 9;
                int nt = rest & 7, kb = (rest >> 3) & 3, s = rest >> 5;
                int k = kb * 32 + ((lane >> 4) * 8) + j;
                int n = nt * 16 + (lane & 15);
                Wf[g2] = f2bf(W[((size_t)s * D + k) * D + n]);
            }
        }
        return;
    }

    // ------------------------------- scatter path -------------------------
    for (int i = tid; i < NC; i += 256) h[i] = 0;
    __syncthreads();

    int s  = blockIdx.x / CTPS;
    int tb = (blockIdx.x % CTPS) * CTILE;
    int n  = N_EDGES - tb; if (n > CTILE) n = CTILE;
    const int*   rp = rows + (size_t)s * N_EDGES + tb;
    const int*   cp = cols + (size_t)s * N_EDGES + tb;
    const float* vp = vals + (size_t)s * N_EDGES + tb;

    int bk[8], grow[8];
    #pragma unroll
    for (int i = 0; i < 8; ++i) {
        int idx = tid + i * 256;
        bk[i] = -1;
        if (idx < n) {
            grow[i] = s * N_NODES + rp[idx];
            bk[i] = grow[i] >> 9;
            atomicAdd(&h[bk[i]], 1);
        }
    }
    __syncthreads();
    for (int i = tid; i < NC; i += 256) {
        base[i] = atomicAdd(&coarse_wptr[i], h[i]);   // zero-based count
        h[i] = 0;                                     // reuse as running rank
    }
    __syncthreads();
    #pragma unroll
    for (int i = 0; i < 8; ++i) {
        int idx = tid + i * 256;
        if (idx < n) {
            int rank = atomicAdd(&h[bk[i]], 1);
            int slot = base[bk[i]] + rank;
            if (slot < CAPC) {                   // never at +14 sigma
                unsigned int meta = ((unsigned int)(grow[i] & 511) << 16)
                                  | (unsigned int)cp[idx];
                sortedA[(size_t)bk[i] * CAPC + slot] =
                    make_uint2(meta, __float_as_uint(vp[idx]));
            }
        }
    }
}

// ---------------------------------------------------------------------------
// Bucket sort, 4-way row-split (proven R9/R10): block (c,q) streams the
// whole bucket, full LDS histogram + scan (rows padded to x4 edges), then
// scatters only rows [q*128,(q+1)*128) into the fixed CAPB region + zero
// pad-fill. q=0 writes row_ptr2 (513 entries/bucket, last = end).
// ---------------------------------------------------------------------------
__global__ __launch_bounds__(512) void bucket_sort(
    const int* __restrict__ coarse_wptr, const uint2* __restrict__ sortedA,
    int* __restrict__ row_ptr2, unsigned int* __restrict__ sortedB)
{
    int c  = blockIdx.x >> 2;
    int q  = blockIdx.x & 3;
    int cnt = coarse_wptr[c];
    if (cnt > CAPC) cnt = CAPC;
    int rowlo = q * 128;

    __shared__ int hist[512];
    __shared__ int rank[128];
    __shared__ int fin[128];
    int tid = threadIdx.x;
    hist[tid] = 0;
    __syncthreads();

    const uint2* src = sortedA + (size_t)c * CAPC;
    for (int i = tid; i < cnt; i += 512)
        atomicAdd(&hist[src[i].x >> 16], 1);
    __syncthreads();

    int padded = (hist[tid] + 3) & ~3;           // rows padded to x4 edges
    hist[tid] = padded;
    __syncthreads();
    for (int off = 1; off < 512; off <<= 1) {    // inclusive scan of padded
        int t = (tid >= off) ? hist[tid - off] : 0;
        __syncthreads();
        hist[tid] += t;
        __syncthreads();
    }
    int start = c * CAPB + hist[tid] - padded;
    if ((unsigned)(tid - rowlo) < 128u) {
        rank[tid - rowlo] = start;
        fin [tid - rowlo] = start + padded;
    }
    if (q == 0) {
        row_ptr2[c * 513 + tid] = start;
        if (tid == 511) row_ptr2[c * 513 + 512] = c * CAPB + hist[511];
    }
    __syncthreads();

    auto proc = [&](uint2 e) {
        int lr = (int)(e.x >> 16) - rowlo;
        if ((unsigned)lr < 128u) {
            int r = atomicAdd(&rank[lr], 1);
            sortedB[r] = ((unsigned int)f2bf(__uint_as_float(e.y)) << 16)
                       | (e.x & 0xFFFFu);
        }
    };
    int i = tid;
    for (; i + 1536 < cnt; i += 2048) {          // 4-deep ILP on the loads
        uint2 e0 = src[i], e1 = src[i + 512];
        uint2 e2 = src[i + 1024], e3 = src[i + 1536];
        proc(e0); proc(e1); proc(e2); proc(e3);
    }
    for (; i < cnt; i += 512) proc(src[i]);
    __syncthreads();

    if (tid < 128)                               // zero-fill pads (<=3/row)
        for (int p = rank[tid]; p < fin[tid]; ++p) sortedB[p] = 0;
}

// ---------------------------------------------------------------------------
// FUSED gather + MFMA GEMM. Block = 16 output nodes. Phase 1: the 4 waves
// gather the 48 rows (3 sup x 16 nodes, 12 rows/wave) with the proven R9
// inner loop (2 halves x 2 unroll = 4 edges in flight, padded rows, pk_fma)
// into a 12.7 KB LDS tile (row stride 132 shorts: gather writes 2-way bank
// alias = free; GEMM reads ~4-way on a tiny phase). Phase 2 (one barrier):
// wave w computes nt = {2w, 2w+1}: 3 sup x 4 kb x 2 = 24 MFMAs, A from LDS,
// B from L2-hot Wf; fused bias+relu epilogue. Kills the 75 MB Yb round-trip
// and the separate GEMM dispatch; block edge count 614 +- 25 -> balanced.
// ---------------------------------------------------------------------------
__global__ __launch_bounds__(256) void gather_gemm(
    const unsigned short* __restrict__ xb, const int* __restrict__ row_ptr2,
    const unsigned int* __restrict__ sortedB,
    const unsigned short* __restrict__ Wf,
    const float* __restrict__ bias, float* __restrict__ out)
{
    __shared__ unsigned short ys[48 * LDSTR];    // 12.7 KB
    __shared__ int rs[48], re[48];
    const int tid  = threadIdx.x;
    const int w    = tid >> 6;
    const int lane = tid & 63;
    const int m0   = blockIdx.x * 16;

    if (tid < 48) {
        int grow = (tid >> 4) * N_NODES + m0 + (tid & 15);
        int rpi  = (grow >> 9) * 513 + (grow & 511);
        rs[tid] = row_ptr2[rpi];
        re[tid] = row_ptr2[rpi + 1];
    }
    __syncthreads();

    // ---- phase 1: gather 12 rows per wave ----
    const int hh = lane >> 5;                    // half index
    const int u  = lane & 31;                    // cols 4u..4u+3
    for (int r = w; r < 48; r += 4) {
        int start = rs[r], end = re[r];
        f32x2 accA = {0.f, 0.f}, accB = {0.f, 0.f};
        for (int j = start; j < end; j += 64) {
            int m = end - j; if (m > 64) m = 64; // multiple of 4
            unsigned int ev = (lane < m) ? sortedB[j + lane] : 0u;
            for (int t = 0; t < m; t += 4) {
                unsigned int e0 = (unsigned int)__shfl((int)ev, t + hh);
                unsigned int e1 = (unsigned int)__shfl((int)ev, t + 2 + hh);
                float v0 = __uint_as_float(e0 & 0xFFFF0000u);
                float v1 = __uint_as_float(e1 & 0xFFFF0000u);
                uint2 X0 = *((const uint2*)(xb + (size_t)(e0 & 0xFFFFu) * D) + u);
                uint2 X1 = *((const uint2*)(xb + (size_t)(e1 & 0xFFFFu) * D) + u);
                f32x2 xa0 = {__uint_as_float(X0.x << 16),
                             __uint_as_float(X0.x & 0xFFFF0000u)};
                f32x2 xb0 = {__uint_as_float(X0.y << 16),
                             __uint_as_float(X0.y & 0xFFFF0000u)};
                f32x2 xa1 = {__uint_as_float(X1.x << 16),
                             __uint_as_float(X1.x & 0xFFFF0000u)};
                f32x2 xb1 = {__uint_as_float(X1.y << 16),
                             __uint_as_float(X1.y & 0xFFFF0000u)};
                accA += v0 * xa0;                // v_pk_fma_f32
                accB += v0 * xb0;
                accA += v1 * xa1;
                accB += v1 * xb1;
            }
        }
        float a0 = accA.x, a1 = accA.y, a2 = accB.x, a3 = accB.y;
        a0 += __shfl_xor(a0, 32);
        a1 += __shfl_xor(a1, 32);
        a2 += __shfl_xor(a2, 32);
        a3 += __shfl_xor(a3, 32);
        if (hh == 0) {
            uint2 o;
            o.x = (unsigned int)f2bf(a0) | ((unsigned int)f2bf(a1) << 16);
            o.y = (unsigned int)f2bf(a2) | ((unsigned int)f2bf(a3) << 16);
            *(uint2*)(ys + r * LDSTR + u * 4) = o;   // 8B-aligned, 2-way free
        }
    }
    __syncthreads();

    // ---- phase 2: MFMA GEMM, wave w -> nt {2w, 2w+1} ----
    const int quad = lane >> 4;
    const int l16  = lane & 15;
    const int nt0  = w * 2;
    f32x4 acc0 = {0.f, 0.f, 0.f, 0.f}, acc1 = {0.f, 0.f, 0.f, 0.f};

    #pragma unroll
    for (int s = 0; s < N_SUP; ++s) {
        #pragma unroll
        for (int kb = 0; kb < 4; ++kb) {
            union { uint2 q[2]; s16x8 v; } A;
            const unsigned short* ap = ys + (s * 16 + l16) * LDSTR
                                          + kb * 32 + quad * 8;
            A.q[0] = *(const uint2*)ap;          // 8B-aligned LDS reads
            A.q[1] = *(const uint2*)(ap + 4);
            const unsigned short* wf = Wf + (size_t)((s * 4 + kb) * 8 + nt0) * 64 * 8
                                          + lane * 8;
            s16x8 b0 = *(const s16x8*)wf;
            s16x8 b1 = *(const s16x8*)(wf + 64 * 8);
            acc0 = __builtin_amdgcn_mfma_f32_16x16x32_bf16(A.v, b0, acc0, 0, 0, 0);
            acc1 = __builtin_amdgcn_mfma_f32_16x16x32_bf16(A.v, b1, acc1, 0, 0, 0);
        }
    }

    #pragma unroll
    for (int p = 0; p < 2; ++p) {
        int col = (nt0 + p) * 16 + l16;
        float bv = bias[col];
        f32x4 a = p ? acc1 : acc0;
        #pragma unroll
        for (int r = 0; r < 4; ++r) {
            int row = m0 + quad * 4 + r;
            out[(size_t)row * D + col] = fmaxf(a[r] + bv, 0.f);
        }
    }
}

extern "C" void kernel_launch(void* const* d_in, const int* in_sizes, int n_in,
                              void* d_out, int out_size, void* d_ws, size_t ws_size,
                              hipStream_t stream)
{
    const float* x         = (const float*)d_in[0];
    const int*   edge_rows = (const int*)  d_in[1];
    const int*   edge_cols = (const int*)  d_in[2];
    const float* edge_vals = (const float*)d_in[3];
    const float* weights   = (const float*)d_in[4];
    const float* bias      = (const float*)d_in[5];
    float* out = (float*)d_out;

    // workspace layout (256B aligned), ~42 MB total
    char* ws = (char*)d_ws;
    size_t off = 0;
    auto alloc = [&](size_t bytes) -> char* {
        char* p = ws + off;
        off += (bytes + 255) & ~(size_t)255;
        return p;
    };
    int*            coarse_wptr = (int*)            alloc(NC * 4);
    int*            row_ptr2    = (int*)            alloc((size_t)NC * 513 * 4);
    unsigned short* xb          = (unsigned short*) alloc((size_t)N_NODES * D * 2);
    unsigned short* Wf          = (unsigned short*) alloc((size_t)N_SUP * D * D * 2);
    uint2*          sortedA     = (uint2*)          alloc((size_t)NC * CAPC * 8);
    unsigned int*   sortedB     = (unsigned int*)   alloc((size_t)NC * CAPB * 4);

    hipMemsetAsync(coarse_wptr, 0, NC * 4, stream);
    prep_scatter<<<SBLKS + XCBLKS + WBLKS, 256, 0, stream>>>(
        edge_rows, edge_cols, edge_vals, coarse_wptr, sortedA,
        (const float4*)x, (ushort4*)xb, weights, Wf);
    bucket_sort <<<NC * 4, 512, 0, stream>>>(coarse_wptr, sortedA,
                                             row_ptr2, sortedB);
    gather_gemm <<<N_NODES / 16, 256, 0, stream>>>(xb, row_ptr2, sortedB,
                                                   Wf, bias, out);
}

// Round 12
// 198.185 us; speedup vs baseline: 1.2308x; 1.1527x over previous
//
#include <hip/hip_runtime.h>

#define N_NODES 50000
#define N_EDGES 640000
#define N_SUP   3
#define D       128
#define NTOT    150000                   // 3 * 50000 global rows
#define E_TOT   1920000
#define NC      293                      // 512-row coarse buckets (grow>>9)
#define CAPC    7680                     // raw cap: mean 6553 + ~14 sigma
#define CAPB    9216                     // padded cap: CAPC + 512*3
#define CTILE   2048
#define CTPS    313                      // ceil(640000/2048) tiles per support
#define SBLKS   (N_SUP * CTPS)           // 939 scatter blocks
#define XCBLKS  3125                     // (50000*128/4)/512 x-convert blocks
#define WBLKS   96                       // 49152/512 W-pack blocks
#define LDSTR   132                      // LDS row stride in shorts (128+4 pad)

typedef __attribute__((ext_vector_type(2))) float f32x2;
typedef __attribute__((ext_vector_type(4))) float f32x4;
typedef __attribute__((ext_vector_type(8))) short s16x8;

__device__ __forceinline__ unsigned short f2bf(float f) {   // RNE
    unsigned int u = __float_as_uint(f);
    u += 0x7FFFu + ((u >> 16) & 1u);
    return (unsigned short)(u >> 16);
}

// ---------------------------------------------------------------------------
// Fused prep + coarse scatter, LDS-REORDERED writes: edges are ranked and
// staged in LDS sorted by bucket with precomputed absolute destinations, so
// the global write loop has consecutive lanes writing consecutive addresses
// within each bucket run (~10 transactions/wave vs 64 scattered).
// Blocks [0,SBLKS) scatter; trailing blocks convert x -> bf16 / W -> frags.
// meta = (local_row<<16) | col.
// ---------------------------------------------------------------------------
__global__ __launch_bounds__(512) void prep_scatter(
    const int* __restrict__ rows, const int* __restrict__ cols,
    const float* __restrict__ vals, int* __restrict__ coarse_wptr,
    uint2* __restrict__ sortedA,
    const float4* __restrict__ x, ushort4* __restrict__ xb,
    const float* __restrict__ W, unsigned short* __restrict__ Wf)
{
    int tid = threadIdx.x;

    if (blockIdx.x >= SBLKS) {                   // -------- convert path ----
        int gid = (blockIdx.x - SBLKS) * 512 + tid;
        if (gid < N_NODES * D / 4) {             // x -> bf16
            float4 v = x[gid];
            ushort4 o;
            o.x = f2bf(v.x); o.y = f2bf(v.y); o.z = f2bf(v.z); o.w = f2bf(v.w);
            xb[gid] = o;
        } else {                                 // W -> MFMA B-fragment order
            int g2 = gid - N_NODES * D / 4;
            if (g2 < N_SUP * D * D) {
                int j    = g2 & 7;
                int lane = (g2 >> 3) & 63;
                int rest = g2 >> 9;
                int nt = rest & 7, kb = (rest >> 3) & 3, s = rest >> 5;
                int k = kb * 32 + ((lane >> 4) * 8) + j;
                int n = nt * 16 + (lane & 15);
                Wf[g2] = f2bf(W[((size_t)s * D + k) * D + n]);
            }
        }
        return;
    }

    // ------------------------------- scatter path -------------------------
    __shared__ int          h[512];              // bucket histogram (padded)
    __shared__ int          toff[512];           // tile-local bucket offsets
    __shared__ int          gbase[512];          // global bucket bases
    __shared__ uint2        stage[CTILE];        // 16 KB bucket-sorted edges
    __shared__ unsigned int dst[CTILE];          // 8 KB absolute dests

    h[tid] = 0;
    __syncthreads();

    int s  = blockIdx.x / CTPS;
    int tb = (blockIdx.x % CTPS) * CTILE;
    int n  = N_EDGES - tb; if (n > CTILE) n = CTILE;
    const int*   rp = rows + (size_t)s * N_EDGES + tb;
    const int*   cp = cols + (size_t)s * N_EDGES + tb;
    const float* vp = vals + (size_t)s * N_EDGES + tb;

    int bk[4], rk[4]; uint2 ed[4];
    #pragma unroll
    for (int i = 0; i < 4; ++i) {
        int idx = tid + i * 512;
        bk[i] = -1;
        if (idx < n) {
            int grow = s * N_NODES + rp[idx];
            bk[i] = grow >> 9;
            rk[i] = atomicAdd(&h[bk[i]], 1);     // within-tile bucket rank
            ed[i] = make_uint2(((unsigned int)(grow & 511) << 16)
                               | (unsigned int)cp[idx],
                               __float_as_uint(vp[idx]));
        }
    }
    __syncthreads();
    int cntb = h[tid];                           // this thread's bucket count
    __syncthreads();
    for (int off = 1; off < 512; off <<= 1) {    // inclusive scan
        int t = (tid >= off) ? h[tid - off] : 0;
        __syncthreads();
        h[tid] += t;
        __syncthreads();
    }
    toff[tid]  = h[tid] - cntb;                  // tile-local exclusive
    gbase[tid] = (cntb > 0) ? atomicAdd(&coarse_wptr[tid], cntb) : 0;
    __syncthreads();

    #pragma unroll
    for (int i = 0; i < 4; ++i) {
        if (bk[i] >= 0) {
            int slot = toff[bk[i]] + rk[i];
            int gslot = gbase[bk[i]] + rk[i];
            stage[slot] = ed[i];
            dst[slot] = (gslot < CAPC)
                      ? (unsigned int)(bk[i] * CAPC + gslot)
                      : 0xFFFFFFFFu;             // never at +14 sigma
        }
    }
    __syncthreads();
    for (int j = tid; j < n; j += 512) {         // coalesced run writes
        unsigned int d = dst[j];
        if (d != 0xFFFFFFFFu) sortedA[d] = stage[j];
    }
}

// ---------------------------------------------------------------------------
// Bucket sort, single pass: ONE block per bucket (512 threads) loads ALL
// bucket edges into REGISTERS (<=15/thread) once, LDS histogram + scan (rows
// padded to x4 edges), scatter from registers, zero pad-fill. Cuts the R11
// 8x bucket re-streaming (123 MB) to a single 15.4 MB read.
// row_ptr2: 513 entries/bucket, last = bucket end.
// ---------------------------------------------------------------------------
__global__ __launch_bounds__(512) void bucket_sort(
    const int* __restrict__ coarse_wptr, const uint2* __restrict__ sortedA,
    int* __restrict__ row_ptr2, unsigned int* __restrict__ sortedB)
{
    int c  = blockIdx.x;
    int cnt = coarse_wptr[c];
    if (cnt > CAPC) cnt = CAPC;

    __shared__ int hist[512];
    __shared__ int rank[512];
    __shared__ int fin[512];
    int tid = threadIdx.x;
    hist[tid] = 0;

    const uint2* src = sortedA + (size_t)c * CAPC;
    uint2 e[15];
    #pragma unroll
    for (int k = 0; k < 15; ++k) {               // 15 independent loads
        int idx = tid + k * 512;
        if (idx < cnt) e[k] = src[idx];
    }
    __syncthreads();
    #pragma unroll
    for (int k = 0; k < 15; ++k) {
        int idx = tid + k * 512;
        if (idx < cnt) atomicAdd(&hist[e[k].x >> 16], 1);
    }
    __syncthreads();

    int padded = (hist[tid] + 3) & ~3;           // rows padded to x4 edges
    hist[tid] = padded;
    __syncthreads();
    for (int off = 1; off < 512; off <<= 1) {    // inclusive scan of padded
        int t = (tid >= off) ? hist[tid - off] : 0;
        __syncthreads();
        hist[tid] += t;
        __syncthreads();
    }
    int start = c * CAPB + hist[tid] - padded;
    rank[tid] = start;
    fin [tid] = start + padded;
    row_ptr2[c * 513 + tid] = start;
    if (tid == 511) row_ptr2[c * 513 + 512] = c * CAPB + hist[511];
    __syncthreads();

    #pragma unroll
    for (int k = 0; k < 15; ++k) {
        int idx = tid + k * 512;
        if (idx < cnt) {
            int r = atomicAdd(&rank[e[k].x >> 16], 1);
            sortedB[r] = ((unsigned int)f2bf(__uint_as_float(e[k].y)) << 16)
                       | (e[k].x & 0xFFFFu);
        }
    }
    __syncthreads();
    for (int p = rank[tid]; p < fin[tid]; ++p) sortedB[p] = 0;
}

// ---------------------------------------------------------------------------
// FUSED gather + MFMA GEMM (proven R11, untouched). Block = 16 output nodes;
// 4 waves gather 48 rows (R9 inner loop) into a 12.7 KB LDS tile, one
// barrier, then 24 MFMAs/wave with fused bias+relu.
// ---------------------------------------------------------------------------
__global__ __launch_bounds__(256) void gather_gemm(
    const unsigned short* __restrict__ xb, const int* __restrict__ row_ptr2,
    const unsigned int* __restrict__ sortedB,
    const unsigned short* __restrict__ Wf,
    const float* __restrict__ bias, float* __restrict__ out)
{
    __shared__ unsigned short ys[48 * LDSTR];    // 12.7 KB
    __shared__ int rs[48], re[48];
    const int tid  = threadIdx.x;
    const int w    = tid >> 6;
    const int lane = tid & 63;
    const int m0   = blockIdx.x * 16;

    if (tid < 48) {
        int grow = (tid >> 4) * N_NODES + m0 + (tid & 15);
        int rpi  = (grow >> 9) * 513 + (grow & 511);
        rs[tid] = row_ptr2[rpi];
        re[tid] = row_ptr2[rpi + 1];
    }
    __syncthreads();

    // ---- phase 1: gather 12 rows per wave ----
    const int hh = lane >> 5;                    // half index
    const int u  = lane & 31;                    // cols 4u..4u+3
    for (int r = w; r < 48; r += 4) {
        int start = rs[r], end = re[r];
        f32x2 accA = {0.f, 0.f}, accB = {0.f, 0.f};
        for (int j = start; j < end; j += 64) {
            int m = end - j; if (m > 64) m = 64; // multiple of 4
            unsigned int ev = (lane < m) ? sortedB[j + lane] : 0u;
            for (int t = 0; t < m; t += 4) {
                unsigned int e0 = (unsigned int)__shfl((int)ev, t + hh);
                unsigned int e1 = (unsigned int)__shfl((int)ev, t + 2 + hh);
                float v0 = __uint_as_float(e0 & 0xFFFF0000u);
                float v1 = __uint_as_float(e1 & 0xFFFF0000u);
                uint2 X0 = *((const uint2*)(xb + (size_t)(e0 & 0xFFFFu) * D) + u);
                uint2 X1 = *((const uint2*)(xb + (size_t)(e1 & 0xFFFFu) * D) + u);
                f32x2 xa0 = {__uint_as_float(X0.x << 16),
                             __uint_as_float(X0.x & 0xFFFF0000u)};
                f32x2 xb0 = {__uint_as_float(X0.y << 16),
                             __uint_as_float(X0.y & 0xFFFF0000u)};
                f32x2 xa1 = {__uint_as_float(X1.x << 16),
                             __uint_as_float(X1.x & 0xFFFF0000u)};
                f32x2 xb1 = {__uint_as_float(X1.y << 16),
                             __uint_as_float(X1.y & 0xFFFF0000u)};
                accA += v0 * xa0;                // v_pk_fma_f32
                accB += v0 * xb0;
                accA += v1 * xa1;
                accB += v1 * xb1;
            }
        }
        float a0 = accA.x, a1 = accA.y, a2 = accB.x, a3 = accB.y;
        a0 += __shfl_xor(a0, 32);
        a1 += __shfl_xor(a1, 32);
        a2 += __shfl_xor(a2, 32);
        a3 += __shfl_xor(a3, 32);
        if (hh == 0) {
            uint2 o;
            o.x = (unsigned int)f2bf(a0) | ((unsigned int)f2bf(a1) << 16);
            o.y = (unsigned int)f2bf(a2) | ((unsigned int)f2bf(a3) << 16);
            *(uint2*)(ys + r * LDSTR + u * 4) = o;   // 8B-aligned, 2-way free
        }
    }
    __syncthreads();

    // ---- phase 2: MFMA GEMM, wave w -> nt {2w, 2w+1} ----
    const int quad = lane >> 4;
    const int l16  = lane & 15;
    const int nt0  = w * 2;
    f32x4 acc0 = {0.f, 0.f, 0.f, 0.f}, acc1 = {0.f, 0.f, 0.f, 0.f};

    #pragma unroll
    for (int s = 0; s < N_SUP; ++s) {
        #pragma unroll
        for (int kb = 0; kb < 4; ++kb) {
            union { uint2 q[2]; s16x8 v; } A;
            const unsigned short* ap = ys + (s * 16 + l16) * LDSTR
                                          + kb * 32 + quad * 8;
            A.q[0] = *(const uint2*)ap;          // 8B-aligned LDS reads
            A.q[1] = *(const uint2*)(ap + 4);
            const unsigned short* wf = Wf + (size_t)((s * 4 + kb) * 8 + nt0) * 64 * 8
                                          + lane * 8;
            s16x8 b0 = *(const s16x8*)wf;
            s16x8 b1 = *(const s16x8*)(wf + 64 * 8);
            acc0 = __builtin_amdgcn_mfma_f32_16x16x32_bf16(A.v, b0, acc0, 0, 0, 0);
            acc1 = __builtin_amdgcn_mfma_f32_16x16x32_bf16(A.v, b1, acc1, 0, 0, 0);
        }
    }

    #pragma unroll
    for (int p = 0; p < 2; ++p) {
        int col = (nt0 + p) * 16 + l16;
        float bv = bias[col];
        f32x4 a = p ? acc1 : acc0;
        #pragma unroll
        for (int r = 0; r < 4; ++r) {
            int row = m0 + quad * 4 + r;
            out[(size_t)row * D + col] = fmaxf(a[r] + bv, 0.f);
        }
    }
}

extern "C" void kernel_launch(void* const* d_in, const int* in_sizes, int n_in,
                              void* d_out, int out_size, void* d_ws, size_t ws_size,
                              hipStream_t stream)
{
    const float* x         = (const float*)d_in[0];
    const int*   edge_rows = (const int*)  d_in[1];
    const int*   edge_cols = (const int*)  d_in[2];
    const float* edge_vals = (const float*)d_in[3];
    const float* weights   = (const float*)d_in[4];
    const float* bias      = (const float*)d_in[5];
    float* out = (float*)d_out;

    // workspace layout (256B aligned), ~42 MB total
    char* ws = (char*)d_ws;
    size_t off = 0;
    auto alloc = [&](size_t bytes) -> char* {
        char* p = ws + off;
        off += (bytes + 255) & ~(size_t)255;
        return p;
    };
    int*            coarse_wptr = (int*)            alloc(512 * 4);
    int*            row_ptr2    = (int*)            alloc((size_t)NC * 513 * 4);
    unsigned short* xb          = (unsigned short*) alloc((size_t)N_NODES * D * 2);
    unsigned short* Wf          = (unsigned short*) alloc((size_t)N_SUP * D * D * 2);
    uint2*          sortedA     = (uint2*)          alloc((size_t)NC * CAPC * 8);
    unsigned int*   sortedB     = (unsigned int*)   alloc((size_t)NC * CAPB * 4);

    hipMemsetAsync(coarse_wptr, 0, 512 * 4, stream);
    prep_scatter<<<SBLKS + XCBLKS + WBLKS, 512, 0, stream>>>(
        edge_rows, edge_cols, edge_vals, coarse_wptr, sortedA,
        (const float4*)x, (ushort4*)xb, weights, Wf);
    bucket_sort <<<NC, 512, 0, stream>>>(coarse_wptr, sortedA,
                                         row_ptr2, sortedB);
    gather_gemm <<<N_NODES / 16, 256, 0, stream>>>(xb, row_ptr2, sortedB,
                                                   Wf, bias, out);
}